// Round 1
// baseline (5684.509 us; speedup 1.0000x reference)
//
#include <hip/hip_runtime.h>
#include <math.h>

#define NQ    32768
#define DDIM  256
#define NCLS  3
#define CELLS 512
#define STOT  1536   // NCLS*CELLS

// ---- monotone float<->uint encoding for atomicMax on floats ----
__device__ __forceinline__ unsigned enc_f(float f) {
    unsigned b = __float_as_uint(f);
    return (b & 0x80000000u) ? ~b : (b | 0x80000000u);
}
__device__ __forceinline__ float dec_f(unsigned u) {
    return __uint_as_float((u & 0x80000000u) ? (u & 0x7FFFFFFFu) : ~u);
}

// ---------------- partition queries by label ----------------
__global__ void k_part(const int* __restrict__ labels,
                       unsigned* __restrict__ cnt,
                       int* __restrict__ idxbuf) {
    const int i = blockIdx.x * 256 + threadIdx.x;
    if (i >= NQ) return;
    const int c = labels[i];
    const unsigned p = atomicAdd(&cnt[c], 1u);
    idxbuf[c * NQ + (int)p] = i;
}

// ---- read path: fused attention over 1536 memory rows + global col-max ----
// one wave handles 2 queries; online softmax; dots are wave-uniform after the
// shuffle reduce, so we also bank a per-column running max (used as the
// stabilization constant B_j for the update-path softmax; any consistent
// per-column constant >= class max is mathematically exact).
__global__ __launch_bounds__(256) void k_read(const float* __restrict__ Q,
                                              const float* __restrict__ M,
                                              float* __restrict__ out,
                                              unsigned* __restrict__ colmax) {
    __shared__ float wmax[4 * STOT];
    const int tid  = threadIdx.x;
    const int lane = tid & 63;
    const int wid  = tid >> 6;
    for (int r = tid; r < 4 * STOT; r += 256) wmax[r] = -INFINITY;
    __syncthreads();

    const int wave = blockIdx.x * 4 + wid;      // 0..16383, exact fit
    const int i0   = wave * 2;
    const float4 q0 = *(const float4*)(Q + (size_t)i0 * DDIM + lane * 4);
    const float4 q1 = *(const float4*)(Q + (size_t)(i0 + 1) * DDIM + lane * 4);

    float m0 = -INFINITY, m1 = -INFINITY, l0 = 0.f, l1 = 0.f;
    float a0x = 0.f, a0y = 0.f, a0z = 0.f, a0w = 0.f;
    float a1x = 0.f, a1y = 0.f, a1z = 0.f, a1w = 0.f;
    float* wm = wmax + wid * STOT;

    for (int j = 0; j < STOT; ++j) {
        const float4 mv = *(const float4*)(M + (size_t)j * DDIM + lane * 4);
        float d0 = q0.x * mv.x + q0.y * mv.y + q0.z * mv.z + q0.w * mv.w;
        float d1 = q1.x * mv.x + q1.y * mv.y + q1.z * mv.z + q1.w * mv.w;
#pragma unroll
        for (int sh = 1; sh < 64; sh <<= 1) {
            d0 += __shfl_xor(d0, sh, 64);
            d1 += __shfl_xor(d1, sh, 64);
        }
        // bank column max (d0,d1 wave-uniform; one lane stores per j)
        if (lane == (j & 63)) wm[j] = fmaxf(wm[j], fmaxf(d0, d1));
        // online softmax, query 0 (rescale branch is wave-uniform & rare)
        if (d0 > m0) {
            const float s = __expf(m0 - d0);   // m0=-inf first iter -> s=0
            l0 *= s; a0x *= s; a0y *= s; a0z *= s; a0w *= s;
            m0 = d0;
        }
        const float p0 = __expf(d0 - m0);
        l0 += p0;
        a0x = fmaf(p0, mv.x, a0x); a0y = fmaf(p0, mv.y, a0y);
        a0z = fmaf(p0, mv.z, a0z); a0w = fmaf(p0, mv.w, a0w);
        // query 1
        if (d1 > m1) {
            const float s = __expf(m1 - d1);
            l1 *= s; a1x *= s; a1y *= s; a1z *= s; a1w *= s;
            m1 = d1;
        }
        const float p1 = __expf(d1 - m1);
        l1 += p1;
        a1x = fmaf(p1, mv.x, a1x); a1y = fmaf(p1, mv.y, a1y);
        a1z = fmaf(p1, mv.z, a1z); a1w = fmaf(p1, mv.w, a1w);
    }

    const float r0 = 1.f / l0, r1 = 1.f / l1;
    float4 o0, o1;
    o0.x = a0x * r0; o0.y = a0y * r0; o0.z = a0z * r0; o0.w = a0w * r0;
    o1.x = a1x * r1; o1.y = a1y * r1; o1.z = a1z * r1; o1.w = a1w * r1;
    *(float4*)(out + (size_t)i0 * DDIM + lane * 4) = o0;
    *(float4*)(out + (size_t)(i0 + 1) * DDIM + lane * 4) = o1;

    __syncthreads();
    for (int r = tid; r < STOT; r += 256) {
        const float v = fmaxf(fmaxf(wmax[r], wmax[STOT + r]),
                              fmaxf(wmax[2 * STOT + r], wmax[3 * STOT + r]));
        atomicMax(&colmax[r], enc_f(v));
    }
}

// ---- update path: per-(class, 32-cell chunk, query-split) delta GEMM ----
// grid (16 qsplits, 16 jchunks, 3 classes), block 256.
// thread t: jt = t>>3 (local cell), dg = t&7 (32-dim group).
__global__ __launch_bounds__(256) void k_delta(const float* __restrict__ Q,
                                               const float* __restrict__ M,
                                               const int* __restrict__ idxbuf,
                                               const unsigned* __restrict__ cnt,
                                               const unsigned* __restrict__ colmax,
                                               float* __restrict__ colsum,
                                               float* __restrict__ delta) {
    const int c  = blockIdx.z;
    const int jc = blockIdx.y;
    const int qs = blockIdx.x;
    const int n  = (int)cnt[c];
    const int chunk = (n + 15) >> 4;
    const int q0 = qs * chunk;
    const int q1 = (q0 + chunk < n) ? (q0 + chunk) : n;

    __shared__ float Mt[32 * DDIM];   // 32KB: this block's 32 memory rows
    __shared__ float qv[DDIM];
    __shared__ float cmax_s[32];

    const int t = threadIdx.x;
    {
        const float4* src = (const float4*)(M + (size_t)(c * CELLS + jc * 32) * DDIM);
        float4* dst = (float4*)Mt;
        for (int r = t; r < 32 * DDIM / 4; r += 256) dst[r] = src[r];
        if (t < 32) cmax_s[t] = dec_f(colmax[c * CELLS + jc * 32 + t]);
    }
    __syncthreads();
    if (q0 >= q1) return;   // block-uniform; after barrier usage is done below only

    const int jt = t >> 3;
    const int dg = t & 7;
    const float cm = cmax_s[jt];
    float facc[32];
#pragma unroll
    for (int k = 0; k < 32; ++k) facc[k] = 0.f;
    float sacc = 0.f;

    for (int qq = q0; qq < q1; ++qq) {
        const int i = idxbuf[c * NQ + qq];
        const float qval = Q[(size_t)i * DDIM + t];
        __syncthreads();            // previous iteration's qv reads complete
        qv[t] = qval;
        __syncthreads();

        const float4* mrow = (const float4*)(Mt + jt * DDIM + dg * 32);
        const float4* qp   = (const float4*)(qv + dg * 32);
        float4 qr[8];
#pragma unroll
        for (int k = 0; k < 8; ++k) qr[k] = qp[k];
        float part = 0.f;
#pragma unroll
        for (int k = 0; k < 8; ++k) {
            const float4 mv = mrow[k];
            part += mv.x * qr[k].x + mv.y * qr[k].y + mv.z * qr[k].z + mv.w * qr[k].w;
        }
        part += __shfl_xor(part, 1, 64);
        part += __shfl_xor(part, 2, 64);
        part += __shfl_xor(part, 4, 64);
        const float p = __expf(part - cm);
        if (dg == 0) sacc += p;
#pragma unroll
        for (int k = 0; k < 8; ++k) {
            facc[4 * k + 0] = fmaf(p, qr[k].x, facc[4 * k + 0]);
            facc[4 * k + 1] = fmaf(p, qr[k].y, facc[4 * k + 1]);
            facc[4 * k + 2] = fmaf(p, qr[k].z, facc[4 * k + 2]);
            facc[4 * k + 3] = fmaf(p, qr[k].w, facc[4 * k + 3]);
        }
    }

    float* drow = delta + (size_t)(c * CELLS + jc * 32 + jt) * DDIM + dg * 32;
#pragma unroll
    for (int k = 0; k < 32; ++k) atomicAdd(drow + k, facc[k]);
    if (dg == 0) atomicAdd(colsum + c * CELLS + jc * 32 + jt, sacc);
}

// ---- finalize: new = mem + delta/colsum, row-normalize, write out ----
__global__ void k_final(const float* __restrict__ M,
                        const float* __restrict__ delta,
                        const float* __restrict__ colsum,
                        float* __restrict__ out) {
    const int row  = blockIdx.x * 4 + (threadIdx.x >> 6);   // 0..1535
    const int lane = threadIdx.x & 63;
    const float inv = 1.f / colsum[row];
    const float4 mv = *(const float4*)(M + (size_t)row * DDIM + lane * 4);
    const float4 dv = *(const float4*)(delta + (size_t)row * DDIM + lane * 4);
    float4 nv;
    nv.x = fmaf(dv.x, inv, mv.x);
    nv.y = fmaf(dv.y, inv, mv.y);
    nv.z = fmaf(dv.z, inv, mv.z);
    nv.w = fmaf(dv.w, inv, mv.w);
    float ss = nv.x * nv.x + nv.y * nv.y + nv.z * nv.z + nv.w * nv.w;
#pragma unroll
    for (int sh = 1; sh < 64; sh <<= 1) ss += __shfl_xor(ss, sh, 64);
    const float rn = 1.f / fmaxf(sqrtf(ss), 1e-12f);
    nv.x *= rn; nv.y *= rn; nv.z *= rn; nv.w *= rn;
    *(float4*)(out + (size_t)NQ * DDIM + (size_t)row * DDIM + lane * 4) = nv;
}

extern "C" void kernel_launch(void* const* d_in, const int* in_sizes, int n_in,
                              void* d_out, int out_size, void* d_ws, size_t ws_size,
                              hipStream_t stream) {
    const float* Q      = (const float*)d_in[0];
    const int*   labels = (const int*)d_in[1];
    const float* M      = (const float*)d_in[2];
    float* out = (float*)d_out;

    // workspace layout (floats/uints): cnt[4] | colmax[1536] | colsum[1536]
    //                                 | delta[393216] | idxbuf[3*32768]
    unsigned* cnt    = (unsigned*)d_ws;
    unsigned* colmax = cnt + 4;
    float*    colsum = (float*)(colmax + STOT);
    float*    delta  = colsum + STOT;
    int*      idxbuf = (int*)(delta + NCLS * CELLS * DDIM);

    const size_t zero_bytes = (size_t)(4 + STOT + STOT + NCLS * CELLS * DDIM) * 4;
    hipMemsetAsync(d_ws, 0, zero_bytes, stream);

    k_part<<<NQ / 256, 256, 0, stream>>>(labels, cnt, idxbuf);
    k_read<<<NQ / 8, 256, 0, stream>>>(Q, M, out, colmax);
    dim3 gd(16, 16, NCLS);
    k_delta<<<gd, 256, 0, stream>>>(Q, M, idxbuf, cnt, colmax, colsum, delta);
    k_final<<<STOT / 4, 256, 0, stream>>>(M, delta, colsum, out);
}

// Round 2
// 990.686 us; speedup vs baseline: 5.7380x; 5.7380x over previous
//
#include <hip/hip_runtime.h>
#include <math.h>

#define NQ    32768
#define DDIM  256
#define NCLS  3
#define CELLS 512
#define STOT  1536   // NCLS*CELLS

typedef __attribute__((ext_vector_type(8)))  short bf16x8;
typedef __attribute__((ext_vector_type(16))) float f32x16;

// C-fragment row map for 32x32 MFMA: row = (r&3) + 8*(r>>2) + 4*(lane>>5)
#define ROWF(r) (((r) & 3) + 8 * ((r) >> 2) + 4 * lh)

__device__ __forceinline__ f32x16 mfma16(bf16x8 a, bf16x8 b, f32x16 c) {
    return __builtin_amdgcn_mfma_f32_32x32x16_bf16(a, b, c, 0, 0, 0);
}
__device__ __forceinline__ unsigned short f2bf(float f) {   // RNE
    const unsigned u = __float_as_uint(f);
    return (unsigned short)((u + 0x7FFFu + ((u >> 16) & 1u)) >> 16);
}
__device__ __forceinline__ float bf2f(unsigned short b) {
    return __uint_as_float(((unsigned)b) << 16);
}

// ---- convert R x 256 fp32 -> hi/lo bf16 (row-major) + transposed 256 x R ----
__global__ __launch_bounds__(256) void k_convert(const float* __restrict__ src,
        unsigned short* __restrict__ hi, unsigned short* __restrict__ lo,
        unsigned short* __restrict__ hiT, unsigned short* __restrict__ loT, int R) {
    __shared__ unsigned short lh_s[64][65], ll_s[64][65];
    const int r0 = blockIdx.x * 64, k0 = blockIdx.y * 64, t = threadIdx.x;
#pragma unroll
    for (int it = 0; it < 4; ++it) {
        const int idx = t + 256 * it;
        const int rl = idx >> 4, kq = idx & 15;
        const float4 v = *(const float4*)(src + (size_t)(r0 + rl) * DDIM + k0 + kq * 4);
        const unsigned short h0 = f2bf(v.x), h1 = f2bf(v.y), h2 = f2bf(v.z), h3 = f2bf(v.w);
        const unsigned short l0 = f2bf(v.x - bf2f(h0)), l1 = f2bf(v.y - bf2f(h1));
        const unsigned short l2 = f2bf(v.z - bf2f(h2)), l3 = f2bf(v.w - bf2f(h3));
        ushort4 hv; hv.x = h0; hv.y = h1; hv.z = h2; hv.w = h3;
        ushort4 lv; lv.x = l0; lv.y = l1; lv.z = l2; lv.w = l3;
        *(ushort4*)(hi + (size_t)(r0 + rl) * DDIM + k0 + kq * 4) = hv;
        *(ushort4*)(lo + (size_t)(r0 + rl) * DDIM + k0 + kq * 4) = lv;
        lh_s[rl][kq * 4 + 0] = h0; lh_s[rl][kq * 4 + 1] = h1;
        lh_s[rl][kq * 4 + 2] = h2; lh_s[rl][kq * 4 + 3] = h3;
        ll_s[rl][kq * 4 + 0] = l0; ll_s[rl][kq * 4 + 1] = l1;
        ll_s[rl][kq * 4 + 2] = l2; ll_s[rl][kq * 4 + 3] = l3;
    }
    __syncthreads();
#pragma unroll
    for (int it = 0; it < 16; ++it) {
        const int idx = t + 256 * it;           // 0..4095
        const int kl = idx >> 6, rl = idx & 63;
        hiT[(size_t)(k0 + kl) * R + r0 + rl] = lh_s[rl][kl];
        loT[(size_t)(k0 + kl) * R + r0 + rl] = ll_s[rl][kl];
    }
}

// ---- per-row 6*||row|| for Q and M ----
__global__ __launch_bounds__(256) void k_norms(const float* __restrict__ Q,
        const float* __restrict__ M, float* __restrict__ qn6, float* __restrict__ mn6) {
    const int wave = blockIdx.x * 4 + (threadIdx.x >> 6);
    const int lane = threadIdx.x & 63;
    const float* src; float* dst;
    if (wave < NQ) { src = Q + (size_t)wave * DDIM; dst = qn6 + wave; }
    else { const int r = wave - NQ; if (r >= STOT) return;
           src = M + (size_t)r * DDIM; dst = mn6 + r; }
    const float4 v = *(const float4*)(src + lane * 4);
    float ss = v.x * v.x + v.y * v.y + v.z * v.z + v.w * v.w;
#pragma unroll
    for (int sh = 1; sh < 64; sh <<= 1) ss += __shfl_xor(ss, sh, 64);
    if (lane == 0) *dst = 6.0f * sqrtf(ss);
}

// ---- main GEMM pass: logits tile -> P' (row-shifted) + E' (col-shifted, masked, transposed) ----
// grid (12 j-blocks, ch/128 i-blocks); block 128i x 128j, 4 waves (2i x 2j), wave 64x64.
__global__ __launch_bounds__(256) void k_pe(
        const unsigned short* __restrict__ Qhi, const unsigned short* __restrict__ Qlo,
        const unsigned short* __restrict__ Mhi, const unsigned short* __restrict__ Mlo,
        const int* __restrict__ labels, const float* __restrict__ qn6,
        const float* __restrict__ mn6,
        unsigned short* __restrict__ P, unsigned short* __restrict__ ET,
        int ibase, int ch) {
    __shared__ unsigned short tr[4][32][40];   // per-wave transpose tile (pad->80B rows)
    const int t = threadIdx.x, lane = t & 63, wid = t >> 6;
    const int l31 = lane & 31, lh = lane >> 5;
    const int wi = wid >> 1, wj = wid & 1;
    const int iloc0 = blockIdx.y * 128 + wi * 64;   // chunk-local i base of wave
    const int j0    = blockIdx.x * 128 + wj * 64;   // global slot base of wave
    const int cblk  = blockIdx.x >> 2;              // class of this j-block (128 | 512)
    const int krow  = 8 * lh;

    f32x16 acc[2][2] = {};
    const unsigned short* qh0 = Qhi + (size_t)(ibase + iloc0 + l31) * DDIM + krow;
    const unsigned short* qh1 = qh0 + (size_t)32 * DDIM;
    const unsigned short* ql0 = Qlo + (size_t)(ibase + iloc0 + l31) * DDIM + krow;
    const unsigned short* ql1 = ql0 + (size_t)32 * DDIM;
    const unsigned short* mh0 = Mhi + (size_t)(j0 + l31) * DDIM + krow;
    const unsigned short* mh1 = mh0 + (size_t)32 * DDIM;
    const unsigned short* ml0 = Mlo + (size_t)(j0 + l31) * DDIM + krow;
    const unsigned short* ml1 = ml0 + (size_t)32 * DDIM;

#pragma unroll
    for (int ks = 0; ks < 16; ++ks) {
        const int ko = ks * 16;
        const bf16x8 a0h = *(const bf16x8*)(qh0 + ko);
        const bf16x8 a1h = *(const bf16x8*)(qh1 + ko);
        const bf16x8 a0l = *(const bf16x8*)(ql0 + ko);
        const bf16x8 a1l = *(const bf16x8*)(ql1 + ko);
        const bf16x8 b0h = *(const bf16x8*)(mh0 + ko);
        const bf16x8 b1h = *(const bf16x8*)(mh1 + ko);
        const bf16x8 b0l = *(const bf16x8*)(ml0 + ko);
        const bf16x8 b1l = *(const bf16x8*)(ml1 + ko);
        acc[0][0] = mfma16(a0h, b0h, acc[0][0]);
        acc[0][0] = mfma16(a0h, b0l, acc[0][0]);
        acc[0][0] = mfma16(a0l, b0h, acc[0][0]);
        acc[0][1] = mfma16(a0h, b1h, acc[0][1]);
        acc[0][1] = mfma16(a0h, b1l, acc[0][1]);
        acc[0][1] = mfma16(a0l, b1h, acc[0][1]);
        acc[1][0] = mfma16(a1h, b0h, acc[1][0]);
        acc[1][0] = mfma16(a1h, b0l, acc[1][0]);
        acc[1][0] = mfma16(a1l, b0h, acc[1][0]);
        acc[1][1] = mfma16(a1h, b1h, acc[1][1]);
        acc[1][1] = mfma16(a1h, b1l, acc[1][1]);
        acc[1][1] = mfma16(a1l, b1h, acc[1][1]);
    }

#pragma unroll
    for (int ti = 0; ti < 2; ++ti) {
        float qn[16]; unsigned lm = 0;
        const int ig0 = ibase + iloc0 + ti * 32;
#pragma unroll
        for (int r = 0; r < 16; ++r) {
            const int ir = ig0 + ROWF(r);
            qn[r] = qn6[ir];
            lm |= (unsigned)(labels[ir] == cblk) << r;
        }
#pragma unroll
        for (int tj = 0; tj < 2; ++tj) {
            const int jg = j0 + tj * 32 + l31;
            const float mn = mn6[jg];
#pragma unroll
            for (int r = 0; r < 16; ++r) {
                const float lg = acc[ti][tj][r];
                const int il = iloc0 + ti * 32 + ROWF(r);
                P[(size_t)il * STOT + jg] = f2bf(__expf(lg - qn[r]));
                const float e = ((lm >> r) & 1u) ? __expf(lg - mn) : 0.0f;
                tr[wid][l31][ROWF(r)] = f2bf(e);
            }
            // wave-local LDS transpose -> coalesced ET rows
            const int rr = lane >> 1, off = (lane & 1) * 16;
            const unsigned short* lp = &tr[wid][rr][off];
            const bf16x8 w0 = *(const bf16x8*)(lp);
            const bf16x8 w1 = *(const bf16x8*)(lp + 8);
            unsigned short* erow = ET + (size_t)(j0 + tj * 32 + rr) * ch + iloc0 + ti * 32 + off;
            *(bf16x8*)(erow)     = w0;
            *(bf16x8*)(erow + 8) = w1;
        }
    }
}

// ---- row sums of P' (-> rowsum) and row sums of ET (-> colsum, atomic) ----
__global__ __launch_bounds__(256) void k_sums(const unsigned short* __restrict__ P,
        const unsigned short* __restrict__ ET, float* __restrict__ rowsum,
        float* __restrict__ colsum, int ch) {
    const int wave = blockIdx.x * 4 + (threadIdx.x >> 6);
    const int lane = threadIdx.x & 63;
    if (wave < ch) {
        const unsigned short* row = P + (size_t)wave * STOT;
        float s = 0.f;
        for (int b = 0; b < STOT / 512; ++b) {
            const bf16x8 v = *(const bf16x8*)(row + b * 512 + lane * 8);
#pragma unroll
            for (int e = 0; e < 8; ++e) s += bf2f((unsigned short)v[e]);
        }
#pragma unroll
        for (int sh = 1; sh < 64; sh <<= 1) s += __shfl_xor(s, sh, 64);
        if (lane == 0) rowsum[wave] = s;
    } else {
        const int j = wave - ch; if (j >= STOT) return;
        const unsigned short* row = ET + (size_t)j * ch;
        float s = 0.f;
        for (int b = 0; b < ch / 512; ++b) {
            const bf16x8 v = *(const bf16x8*)(row + b * 512 + lane * 8);
#pragma unroll
            for (int e = 0; e < 8; ++e) s += bf2f((unsigned short)v[e]);
        }
#pragma unroll
        for (int sh = 1; sh < 64; sh <<= 1) s += __shfl_xor(s, sh, 64);
        if (lane == 0) atomicAdd(&colsum[j], s);
    }
}

// ---- PV: out0 rows = (P' @ (Vhi+Vlo)) / rowsum ----
// grid ch/64 blocks; block 64i x 256d, 4 waves (d), wave 64i x 64d.
__global__ __launch_bounds__(256) void k_pv(const unsigned short* __restrict__ P,
        const unsigned short* __restrict__ MhiT, const unsigned short* __restrict__ MloT,
        const float* __restrict__ rowsum, float* __restrict__ out, int ibase) {
    const int t = threadIdx.x, lane = t & 63, wid = t >> 6;
    const int l31 = lane & 31, lh = lane >> 5;
    const int iloc0 = blockIdx.x * 64;
    const int d0 = wid * 64;
    const int krow = 8 * lh;
    f32x16 acc[2][2] = {};
    const unsigned short* p0 = P + (size_t)(iloc0 + l31) * STOT + krow;
    const unsigned short* p1 = p0 + (size_t)32 * STOT;
    const unsigned short* vh0 = MhiT + (size_t)(d0 + l31) * STOT + krow;
    const unsigned short* vh1 = vh0 + (size_t)32 * STOT;
    const unsigned short* vl0 = MloT + (size_t)(d0 + l31) * STOT + krow;
    const unsigned short* vl1 = vl0 + (size_t)32 * STOT;
    for (int ks = 0; ks < STOT / 16; ++ks) {
        const int ko = ks * 16;
        const bf16x8 a0 = *(const bf16x8*)(p0 + ko);
        const bf16x8 a1 = *(const bf16x8*)(p1 + ko);
        const bf16x8 b0h = *(const bf16x8*)(vh0 + ko);
        const bf16x8 b1h = *(const bf16x8*)(vh1 + ko);
        const bf16x8 b0l = *(const bf16x8*)(vl0 + ko);
        const bf16x8 b1l = *(const bf16x8*)(vl1 + ko);
        acc[0][0] = mfma16(a0, b0h, acc[0][0]); acc[0][0] = mfma16(a0, b0l, acc[0][0]);
        acc[0][1] = mfma16(a0, b1h, acc[0][1]); acc[0][1] = mfma16(a0, b1l, acc[0][1]);
        acc[1][0] = mfma16(a1, b0h, acc[1][0]); acc[1][0] = mfma16(a1, b0l, acc[1][0]);
        acc[1][1] = mfma16(a1, b1h, acc[1][1]); acc[1][1] = mfma16(a1, b1l, acc[1][1]);
    }
#pragma unroll
    for (int ti = 0; ti < 2; ++ti) {
        float rs[16];
#pragma unroll
        for (int r = 0; r < 16; ++r) rs[r] = rowsum[iloc0 + ti * 32 + ROWF(r)];
#pragma unroll
        for (int td = 0; td < 2; ++td) {
#pragma unroll
            for (int r = 0; r < 16; ++r) {
                const int ig = ibase + iloc0 + ti * 32 + ROWF(r);
                out[(size_t)ig * DDIM + d0 + td * 32 + l31] = acc[ti][td][r] / rs[r];
            }
        }
    }
}

// ---- delta: delta[j][d] += sum_i ET[j][i] * (Qhi+Qlo)[i][d] ----
// grid (12 j, 2 d, 4 isplit); block 128j x 128d, 4 waves (2j x 2d).
__global__ __launch_bounds__(256) void k_delta4(const unsigned short* __restrict__ ET,
        const unsigned short* __restrict__ QhiT, const unsigned short* __restrict__ QloT,
        float* __restrict__ delta, int ibase, int ch) {
    const int t = threadIdx.x, lane = t & 63, wid = t >> 6;
    const int l31 = lane & 31, lh = lane >> 5;
    const int wj = wid >> 1, wd = wid & 1;
    const int j0 = blockIdx.x * 128 + wj * 64;
    const int d0 = blockIdx.y * 128 + wd * 64;
    const int i0 = blockIdx.z * (ch / 4);
    const int krow = 8 * lh;
    f32x16 acc[2][2] = {};
    const unsigned short* e0 = ET + (size_t)(j0 + l31) * ch + i0 + krow;
    const unsigned short* e1 = e0 + (size_t)32 * ch;
    const unsigned short* qh0 = QhiT + (size_t)(d0 + l31) * NQ + ibase + i0 + krow;
    const unsigned short* qh1 = qh0 + (size_t)32 * NQ;
    const unsigned short* ql0 = QloT + (size_t)(d0 + l31) * NQ + ibase + i0 + krow;
    const unsigned short* ql1 = ql0 + (size_t)32 * NQ;
    const int kiters = ch / 64;   // (ch/4)/16
    for (int ks = 0; ks < kiters; ++ks) {
        const int ko = ks * 16;
        const bf16x8 a0 = *(const bf16x8*)(e0 + ko);
        const bf16x8 a1 = *(const bf16x8*)(e1 + ko);
        const bf16x8 b0h = *(const bf16x8*)(qh0 + ko);
        const bf16x8 b1h = *(const bf16x8*)(qh1 + ko);
        const bf16x8 b0l = *(const bf16x8*)(ql0 + ko);
        const bf16x8 b1l = *(const bf16x8*)(ql1 + ko);
        acc[0][0] = mfma16(a0, b0h, acc[0][0]); acc[0][0] = mfma16(a0, b0l, acc[0][0]);
        acc[0][1] = mfma16(a0, b1h, acc[0][1]); acc[0][1] = mfma16(a0, b1l, acc[0][1]);
        acc[1][0] = mfma16(a1, b0h, acc[1][0]); acc[1][0] = mfma16(a1, b0l, acc[1][0]);
        acc[1][1] = mfma16(a1, b1h, acc[1][1]); acc[1][1] = mfma16(a1, b1l, acc[1][1]);
    }
#pragma unroll
    for (int tj = 0; tj < 2; ++tj) {
#pragma unroll
        for (int td = 0; td < 2; ++td) {
#pragma unroll
            for (int r = 0; r < 16; ++r) {
                const int jr = j0 + tj * 32 + ROWF(r);
                atomicAdd(&delta[(size_t)jr * DDIM + d0 + td * 32 + l31], acc[tj][td][r]);
            }
        }
    }
}

// ---- finalize memory: new = M + delta/colsum, row-normalize ----
__global__ void k_final(const float* __restrict__ M,
                        const float* __restrict__ delta,
                        const float* __restrict__ colsum,
                        float* __restrict__ out) {
    const int row  = blockIdx.x * 4 + (threadIdx.x >> 6);
    const int lane = threadIdx.x & 63;
    const float inv = 1.f / colsum[row];
    const float4 mv = *(const float4*)(M + (size_t)row * DDIM + lane * 4);
    const float4 dv = *(const float4*)(delta + (size_t)row * DDIM + lane * 4);
    float4 nv;
    nv.x = fmaf(dv.x, inv, mv.x);
    nv.y = fmaf(dv.y, inv, mv.y);
    nv.z = fmaf(dv.z, inv, mv.z);
    nv.w = fmaf(dv.w, inv, mv.w);
    float ss = nv.x * nv.x + nv.y * nv.y + nv.z * nv.z + nv.w * nv.w;
#pragma unroll
    for (int sh = 1; sh < 64; sh <<= 1) ss += __shfl_xor(ss, sh, 64);
    const float rn = 1.f / fmaxf(sqrtf(ss), 1e-12f);
    nv.x *= rn; nv.y *= rn; nv.z *= rn; nv.w *= rn;
    *(float4*)(out + (size_t)NQ * DDIM + (size_t)row * DDIM + lane * 4) = nv;
}

extern "C" void kernel_launch(void* const* d_in, const int* in_sizes, int n_in,
                              void* d_out, int out_size, void* d_ws, size_t ws_size,
                              hipStream_t stream) {
    const float* Q      = (const float*)d_in[0];
    const int*   labels = (const int*)d_in[1];
    const float* M      = (const float*)d_in[2];
    float* out = (float*)d_out;

    // ---- workspace layout ----
    char* p = (char*)d_ws;
    float* colsum = (float*)p;          p += (size_t)STOT * 4;
    float* delta  = (float*)p;          p += (size_t)STOT * DDIM * 4;
    float* rowsum = (float*)p;          p += (size_t)NQ * 4;
    float* qn6    = (float*)p;          p += (size_t)NQ * 4;
    float* mn6    = (float*)p;          p += (size_t)STOT * 4;
    unsigned short* Qhi  = (unsigned short*)p; p += (size_t)NQ * DDIM * 2;
    unsigned short* Qlo  = (unsigned short*)p; p += (size_t)NQ * DDIM * 2;
    unsigned short* QhiT = (unsigned short*)p; p += (size_t)NQ * DDIM * 2;
    unsigned short* QloT = (unsigned short*)p; p += (size_t)NQ * DDIM * 2;
    unsigned short* Mhi  = (unsigned short*)p; p += (size_t)STOT * DDIM * 2;
    unsigned short* Mlo  = (unsigned short*)p; p += (size_t)STOT * DDIM * 2;
    unsigned short* MhiT = (unsigned short*)p; p += (size_t)STOT * DDIM * 2;
    unsigned short* MloT = (unsigned short*)p; p += (size_t)STOT * DDIM * 2;
    const size_t fixed_bytes = (size_t)(p - (char*)d_ws);

    // adaptive chunking: P' (ch x 1536) + ET (1536 x ch), both bf16
    int nch = 4;
    while (nch < 64 &&
           fixed_bytes + (size_t)(NQ / nch) * STOT * 2 * 2 > ws_size) nch <<= 1;
    const int ch = NQ / nch;
    unsigned short* Pbuf = (unsigned short*)p;
    unsigned short* ETb  = Pbuf + (size_t)ch * STOT;

    hipMemsetAsync(d_ws, 0, (size_t)(STOT + STOT * DDIM) * 4, stream);  // colsum+delta

    k_convert<<<dim3(NQ / 64, 4), 256, 0, stream>>>(Q, Qhi, Qlo, QhiT, QloT, NQ);
    k_convert<<<dim3(STOT / 64, 4), 256, 0, stream>>>(M, Mhi, Mlo, MhiT, MloT, STOT);
    k_norms<<<(NQ + STOT) / 4 / 1, 256, 0, stream>>>(Q, M, qn6, mn6);

    for (int h = 0; h < nch; ++h) {
        const int ibase = h * ch;
        k_pe<<<dim3(12, ch / 128), 256, 0, stream>>>(Qhi, Qlo, Mhi, Mlo, labels,
                                                     qn6, mn6, Pbuf, ETb, ibase, ch);
        k_sums<<<(ch + STOT) / 4, 256, 0, stream>>>(Pbuf, ETb, rowsum + ibase, colsum, ch);
        k_pv<<<ch / 64, 256, 0, stream>>>(Pbuf, MhiT, MloT, rowsum + ibase, out, ibase);
        k_delta4<<<dim3(STOT / 128, 2, 4), 256, 0, stream>>>(ETb, QhiT, QloT, delta, ibase, ch);
    }
    k_final<<<STOT / 4, 256, 0, stream>>>(M, delta, colsum, out);
}

// Round 3
// 568.701 us; speedup vs baseline: 9.9956x; 1.7420x over previous
//
#include <hip/hip_runtime.h>
#include <math.h>

#define NQ    32768
#define DDIM  256
#define NCLS  3
#define CELLS 512
#define STOT  1536   // NCLS*CELLS

typedef __attribute__((ext_vector_type(8)))  short bf16x8;
typedef __attribute__((ext_vector_type(16))) float f32x16;

// C-fragment row map for 32x32 MFMA: row = (r&3) + 8*(r>>2) + 4*(lane>>5)
#define ROWF(r) (((r) & 3) + 8 * ((r) >> 2) + 4 * lh)

__device__ __forceinline__ f32x16 mfma16(bf16x8 a, bf16x8 b, f32x16 c) {
    return __builtin_amdgcn_mfma_f32_32x32x16_bf16(a, b, c, 0, 0, 0);
}
__device__ __forceinline__ unsigned short f2bf(float f) {   // RNE
    const unsigned u = __float_as_uint(f);
    return (unsigned short)((u + 0x7FFFu + ((u >> 16) & 1u)) >> 16);
}
__device__ __forceinline__ float bf2f(unsigned short b) {
    return __uint_as_float(((unsigned)b) << 16);
}

// ---- convert R x 256 fp32 -> hi/lo bf16 (row-major) + transposed hi (256 x R) ----
__global__ __launch_bounds__(256) void k_convert(const float* __restrict__ src,
        unsigned short* __restrict__ hi, unsigned short* __restrict__ lo,
        unsigned short* __restrict__ hiT, int R) {
    __shared__ unsigned short lh_s[64][65];
    const int r0 = blockIdx.x * 64, k0 = blockIdx.y * 64, t = threadIdx.x;
#pragma unroll
    for (int it = 0; it < 4; ++it) {
        const int idx = t + 256 * it;
        const int rl = idx >> 4, kq = idx & 15;
        const float4 v = *(const float4*)(src + (size_t)(r0 + rl) * DDIM + k0 + kq * 4);
        const unsigned short h0 = f2bf(v.x), h1 = f2bf(v.y), h2 = f2bf(v.z), h3 = f2bf(v.w);
        const unsigned short l0 = f2bf(v.x - bf2f(h0)), l1 = f2bf(v.y - bf2f(h1));
        const unsigned short l2 = f2bf(v.z - bf2f(h2)), l3 = f2bf(v.w - bf2f(h3));
        ushort4 hv; hv.x = h0; hv.y = h1; hv.z = h2; hv.w = h3;
        ushort4 lv; lv.x = l0; lv.y = l1; lv.z = l2; lv.w = l3;
        *(ushort4*)(hi + (size_t)(r0 + rl) * DDIM + k0 + kq * 4) = hv;
        *(ushort4*)(lo + (size_t)(r0 + rl) * DDIM + k0 + kq * 4) = lv;
        lh_s[rl][kq * 4 + 0] = h0; lh_s[rl][kq * 4 + 1] = h1;
        lh_s[rl][kq * 4 + 2] = h2; lh_s[rl][kq * 4 + 3] = h3;
    }
    __syncthreads();
#pragma unroll
    for (int it = 0; it < 16; ++it) {
        const int idx = t + 256 * it;           // 0..4095
        const int kl = idx >> 6, rl = idx & 63;
        hiT[(size_t)(k0 + kl) * R + r0 + rl] = lh_s[rl][kl];
    }
}

// ---- per-row 6*||row|| for Q and M ----
__global__ __launch_bounds__(256) void k_norms(const float* __restrict__ Q,
        const float* __restrict__ M, float* __restrict__ qn6, float* __restrict__ mn6) {
    const int wave = blockIdx.x * 4 + (threadIdx.x >> 6);
    const int lane = threadIdx.x & 63;
    const float* src; float* dst;
    if (wave < NQ) { src = Q + (size_t)wave * DDIM; dst = qn6 + wave; }
    else { const int r = wave - NQ; if (r >= STOT) return;
           src = M + (size_t)r * DDIM; dst = mn6 + r; }
    const float4 v = *(const float4*)(src + lane * 4);
    float ss = v.x * v.x + v.y * v.y + v.z * v.z + v.w * v.w;
#pragma unroll
    for (int sh = 1; sh < 64; sh <<= 1) ss += __shfl_xor(ss, sh, 64);
    if (lane == 0) *dst = 6.0f * sqrtf(ss);
}

// ---- main GEMM pass: logits tile -> P' (row-shifted) + E' (col-shifted, masked, transposed) ----
// grid (12 j-blocks, ch/128 i-blocks); block 128i x 128j, 4 waves (2i x 2j), wave 64x64.
__global__ __launch_bounds__(256) void k_pe(
        const unsigned short* __restrict__ Qhi, const unsigned short* __restrict__ Qlo,
        const unsigned short* __restrict__ Mhi, const unsigned short* __restrict__ Mlo,
        const int* __restrict__ labels, const float* __restrict__ qn6,
        const float* __restrict__ mn6,
        unsigned short* __restrict__ P, unsigned short* __restrict__ ET,
        int ibase, int ch) {
    __shared__ unsigned short tr[4][32][40];   // per-wave transpose tile (pad->80B rows)
    const int t = threadIdx.x, lane = t & 63, wid = t >> 6;
    const int l31 = lane & 31, lh = lane >> 5;
    const int wi = wid >> 1, wj = wid & 1;
    const int iloc0 = blockIdx.y * 128 + wi * 64;   // chunk-local i base of wave
    const int j0    = blockIdx.x * 128 + wj * 64;   // global slot base of wave
    const int cblk  = blockIdx.x >> 2;              // class of this j-block (128 | 512)
    const int krow  = 8 * lh;

    f32x16 acc[2][2] = {};
    const unsigned short* qh0 = Qhi + (size_t)(ibase + iloc0 + l31) * DDIM + krow;
    const unsigned short* qh1 = qh0 + (size_t)32 * DDIM;
    const unsigned short* ql0 = Qlo + (size_t)(ibase + iloc0 + l31) * DDIM + krow;
    const unsigned short* ql1 = ql0 + (size_t)32 * DDIM;
    const unsigned short* mh0 = Mhi + (size_t)(j0 + l31) * DDIM + krow;
    const unsigned short* mh1 = mh0 + (size_t)32 * DDIM;
    const unsigned short* ml0 = Mlo + (size_t)(j0 + l31) * DDIM + krow;
    const unsigned short* ml1 = ml0 + (size_t)32 * DDIM;

#pragma unroll
    for (int ks = 0; ks < 16; ++ks) {
        const int ko = ks * 16;
        const bf16x8 a0h = *(const bf16x8*)(qh0 + ko);
        const bf16x8 a1h = *(const bf16x8*)(qh1 + ko);
        const bf16x8 a0l = *(const bf16x8*)(ql0 + ko);
        const bf16x8 a1l = *(const bf16x8*)(ql1 + ko);
        const bf16x8 b0h = *(const bf16x8*)(mh0 + ko);
        const bf16x8 b1h = *(const bf16x8*)(mh1 + ko);
        const bf16x8 b0l = *(const bf16x8*)(ml0 + ko);
        const bf16x8 b1l = *(const bf16x8*)(ml1 + ko);
        acc[0][0] = mfma16(a0h, b0h, acc[0][0]);
        acc[0][0] = mfma16(a0h, b0l, acc[0][0]);
        acc[0][0] = mfma16(a0l, b0h, acc[0][0]);
        acc[0][1] = mfma16(a0h, b1h, acc[0][1]);
        acc[0][1] = mfma16(a0h, b1l, acc[0][1]);
        acc[0][1] = mfma16(a0l, b1h, acc[0][1]);
        acc[1][0] = mfma16(a1h, b0h, acc[1][0]);
        acc[1][0] = mfma16(a1h, b0l, acc[1][0]);
        acc[1][0] = mfma16(a1l, b0h, acc[1][0]);
        acc[1][1] = mfma16(a1h, b1h, acc[1][1]);
        acc[1][1] = mfma16(a1h, b1l, acc[1][1]);
        acc[1][1] = mfma16(a1l, b1h, acc[1][1]);
    }

#pragma unroll
    for (int ti = 0; ti < 2; ++ti) {
        float qn[16]; unsigned lm = 0;
        const int ig0 = ibase + iloc0 + ti * 32;
#pragma unroll
        for (int r = 0; r < 16; ++r) {
            const int ir = ig0 + ROWF(r);
            qn[r] = qn6[ir];
            lm |= (unsigned)(labels[ir] == cblk) << r;
        }
#pragma unroll
        for (int tj = 0; tj < 2; ++tj) {
            const int jg = j0 + tj * 32 + l31;
            const float mn = mn6[jg];
#pragma unroll
            for (int r = 0; r < 16; ++r) {
                const float lg = acc[ti][tj][r];
                const int il = iloc0 + ti * 32 + ROWF(r);
                P[(size_t)il * STOT + jg] = f2bf(__expf(lg - qn[r]));
                const float e = ((lm >> r) & 1u) ? __expf(lg - mn) : 0.0f;
                tr[wid][l31][ROWF(r)] = f2bf(e);
            }
            // wave-local LDS transpose -> coalesced ET rows
            const int rr = lane >> 1, off = (lane & 1) * 16;
            const unsigned short* lp = &tr[wid][rr][off];
            const bf16x8 w0 = *(const bf16x8*)(lp);
            const bf16x8 w1 = *(const bf16x8*)(lp + 8);
            unsigned short* erow = ET + (size_t)(j0 + tj * 32 + rr) * ch + iloc0 + ti * 32 + off;
            *(bf16x8*)(erow)     = w0;
            *(bf16x8*)(erow + 8) = w1;
        }
    }
}

// ---- PV + fused rowsum: out rows = (P' @ Mhi^T) / rowsum(P') ----
// block 256 = 4 waves; wave = 32 q-rows x 64 d (wid selects d); grid ch/32.
__global__ __launch_bounds__(256) void k_pv(const unsigned short* __restrict__ P,
        const unsigned short* __restrict__ MhiT,
        float* __restrict__ out, int ibase) {
    const int t = threadIdx.x, lane = t & 63, wid = t >> 6;
    const int l31 = lane & 31, lh = lane >> 5;
    const int iloc0 = blockIdx.x * 32;
    const int d0 = wid * 64;
    const int krow = 8 * lh;

    bf16x8 bones;
    const short ob = (l31 == 0) ? (short)0x3F80 : (short)0;
#pragma unroll
    for (int e = 0; e < 8; ++e) bones[e] = ob;

    f32x16 acc[2] = {};
    f32x16 accS = {};
    const unsigned short* p0  = P + (size_t)(iloc0 + l31) * STOT + krow;
    const unsigned short* vh0 = MhiT + (size_t)(d0 + l31) * STOT + krow;
    const unsigned short* vh1 = vh0 + (size_t)32 * STOT;
    for (int ks = 0; ks < STOT / 16; ++ks) {
        const int ko = ks * 16;
        const bf16x8 a0 = *(const bf16x8*)(p0 + ko);
        const bf16x8 b0 = *(const bf16x8*)(vh0 + ko);
        const bf16x8 b1 = *(const bf16x8*)(vh1 + ko);
        acc[0] = mfma16(a0, b0, acc[0]);
        acc[1] = mfma16(a0, b1, acc[1]);
        accS   = mfma16(a0, bones, accS);   // col 0 of accS = rowsum slice
    }
    // rowsum for row ROWF(r) lives in accS[r] of lane (l31==0, same lh)
    float rinv[16];
#pragma unroll
    for (int r = 0; r < 16; ++r) rinv[r] = 1.f / __shfl(accS[r], lh << 5, 64);
#pragma unroll
    for (int td = 0; td < 2; ++td) {
#pragma unroll
        for (int r = 0; r < 16; ++r) {
            const int ig = ibase + iloc0 + ROWF(r);
            out[(size_t)ig * DDIM + d0 + td * 32 + l31] = acc[td][r] * rinv[r];
        }
    }
}

// ---- delta + fused colsum: delta[j][d] += sum_i ET[j][i] * Qhi^T[d][i] ----
// grid (12 j, 2 d, ch/512 ksplit); block 128j x 128d, 4 waves (2j x 2d).
__global__ __launch_bounds__(256) void k_delta4(const unsigned short* __restrict__ ET,
        const unsigned short* __restrict__ QhiT,
        float* __restrict__ delta, float* __restrict__ colsum, int ibase, int ch) {
    const int t = threadIdx.x, lane = t & 63, wid = t >> 6;
    const int l31 = lane & 31, lh = lane >> 5;
    const int wj = wid >> 1, wd = wid & 1;
    const int j0 = blockIdx.x * 128 + wj * 64;
    const int d0 = blockIdx.y * 128 + wd * 64;
    const int i0 = blockIdx.z * 512;
    const int krow = 8 * lh;

    bf16x8 bones;
    const short ob = (l31 == 0) ? (short)0x3F80 : (short)0;
#pragma unroll
    for (int e = 0; e < 8; ++e) bones[e] = ob;

    f32x16 acc[2][2] = {};
    f32x16 accS0 = {}, accS1 = {};
    const unsigned short* e0 = ET + (size_t)(j0 + l31) * ch + i0 + krow;
    const unsigned short* e1 = e0 + (size_t)32 * ch;
    const unsigned short* qh0 = QhiT + (size_t)(d0 + l31) * NQ + ibase + i0 + krow;
    const unsigned short* qh1 = qh0 + (size_t)32 * NQ;
#pragma unroll 4
    for (int ks = 0; ks < 32; ++ks) {
        const int ko = ks * 16;
        const bf16x8 a0 = *(const bf16x8*)(e0 + ko);
        const bf16x8 a1 = *(const bf16x8*)(e1 + ko);
        const bf16x8 b0 = *(const bf16x8*)(qh0 + ko);
        const bf16x8 b1 = *(const bf16x8*)(qh1 + ko);
        acc[0][0] = mfma16(a0, b0, acc[0][0]);
        acc[0][1] = mfma16(a0, b1, acc[0][1]);
        acc[1][0] = mfma16(a1, b0, acc[1][0]);
        acc[1][1] = mfma16(a1, b1, acc[1][1]);
        accS0 = mfma16(a0, bones, accS0);
        accS1 = mfma16(a1, bones, accS1);
    }
#pragma unroll
    for (int tj = 0; tj < 2; ++tj) {
#pragma unroll
        for (int td = 0; td < 2; ++td) {
#pragma unroll
            for (int r = 0; r < 16; ++r) {
                const int jr = j0 + tj * 32 + ROWF(r);
                atomicAdd(&delta[(size_t)jr * DDIM + d0 + td * 32 + l31], acc[tj][td][r]);
            }
        }
    }
    if (wd == 0 && l31 == 0) {   // lanes 0 and 32 (lh=0/1) cover all 32 rows
#pragma unroll
        for (int r = 0; r < 16; ++r) {
            atomicAdd(&colsum[j0 + ROWF(r)], accS0[r]);
            atomicAdd(&colsum[j0 + 32 + ROWF(r)], accS1[r]);
        }
    }
}

// ---- finalize memory: new = M + delta/colsum, row-normalize ----
__global__ void k_final(const float* __restrict__ M,
                        const float* __restrict__ delta,
                        const float* __restrict__ colsum,
                        float* __restrict__ out) {
    const int row  = blockIdx.x * 4 + (threadIdx.x >> 6);
    const int lane = threadIdx.x & 63;
    const float inv = 1.f / colsum[row];
    const float4 mv = *(const float4*)(M + (size_t)row * DDIM + lane * 4);
    const float4 dv = *(const float4*)(delta + (size_t)row * DDIM + lane * 4);
    float4 nv;
    nv.x = fmaf(dv.x, inv, mv.x);
    nv.y = fmaf(dv.y, inv, mv.y);
    nv.z = fmaf(dv.z, inv, mv.z);
    nv.w = fmaf(dv.w, inv, mv.w);
    float ss = nv.x * nv.x + nv.y * nv.y + nv.z * nv.z + nv.w * nv.w;
#pragma unroll
    for (int sh = 1; sh < 64; sh <<= 1) ss += __shfl_xor(ss, sh, 64);
    const float rn = 1.f / fmaxf(sqrtf(ss), 1e-12f);
    nv.x *= rn; nv.y *= rn; nv.z *= rn; nv.w *= rn;
    *(float4*)(out + (size_t)NQ * DDIM + (size_t)row * DDIM + lane * 4) = nv;
}

extern "C" void kernel_launch(void* const* d_in, const int* in_sizes, int n_in,
                              void* d_out, int out_size, void* d_ws, size_t ws_size,
                              hipStream_t stream) {
    const float* Q      = (const float*)d_in[0];
    const int*   labels = (const int*)d_in[1];
    const float* M      = (const float*)d_in[2];
    float* out = (float*)d_out;

    // ---- workspace layout (colsum+delta first: they get memset) ----
    char* p = (char*)d_ws;
    float* colsum = (float*)p;          p += (size_t)STOT * 4;
    float* delta  = (float*)p;          p += (size_t)STOT * DDIM * 4;
    float* qn6    = (float*)p;          p += (size_t)NQ * 4;
    float* mn6    = (float*)p;          p += (size_t)STOT * 4;
    unsigned short* Qhi  = (unsigned short*)p; p += (size_t)NQ * DDIM * 2;
    unsigned short* Qlo  = (unsigned short*)p; p += (size_t)NQ * DDIM * 2;
    unsigned short* QhiT = (unsigned short*)p; p += (size_t)NQ * DDIM * 2;
    unsigned short* Mhi  = (unsigned short*)p; p += (size_t)STOT * DDIM * 2;
    unsigned short* Mlo  = (unsigned short*)p; p += (size_t)STOT * DDIM * 2;
    unsigned short* MhiT = (unsigned short*)p; p += (size_t)STOT * DDIM * 2;
    const size_t fixed_bytes = (size_t)(p - (char*)d_ws);

    // adaptive chunking: P' (ch x 1536) + ET (1536 x ch), both bf16
    int nch = 2;
    while (nch < 64 &&
           fixed_bytes + (size_t)(NQ / nch) * STOT * 2 * 2 > ws_size) nch <<= 1;
    const int ch = NQ / nch;
    unsigned short* Pbuf = (unsigned short*)p;
    unsigned short* ETb  = Pbuf + (size_t)ch * STOT;

    hipMemsetAsync(d_ws, 0, (size_t)(STOT + STOT * DDIM) * 4, stream);  // colsum+delta

    k_convert<<<dim3(NQ / 64, 4), 256, 0, stream>>>(Q, Qhi, Qlo, QhiT, NQ);
    k_convert<<<dim3(STOT / 64, 4), 256, 0, stream>>>(M, Mhi, Mlo, MhiT, STOT);
    k_norms<<<(NQ + STOT) / 4, 256, 0, stream>>>(Q, M, qn6, mn6);

    for (int h = 0; h < nch; ++h) {
        const int ibase = h * ch;
        k_pe<<<dim3(12, ch / 128), 256, 0, stream>>>(Qhi, Qlo, Mhi, Mlo, labels,
                                                     qn6, mn6, Pbuf, ETb, ibase, ch);
        k_pv<<<ch / 32, 256, 0, stream>>>(Pbuf, MhiT, out, ibase);
        k_delta4<<<dim3(STOT / 128, 2, ch / 512), 256, 0, stream>>>(ETb, QhiT, delta,
                                                                    colsum, ibase, ch);
    }
    k_final<<<STOT / 4, 256, 0, stream>>>(M, delta, colsum, out);
}

// Round 4
// 374.730 us; speedup vs baseline: 15.1696x; 1.5176x over previous
//
#include <hip/hip_runtime.h>
#include <math.h>

#define NQ    32768
#define DDIM  256
#define NCLS  3
#define CELLS 512
#define STOT  1536   // NCLS*CELLS
#define BK    32

typedef __attribute__((ext_vector_type(8)))  short bf16x8;
typedef __attribute__((ext_vector_type(16))) float f32x16;

// C-fragment row map for 32x32 MFMA: row = (r&3) + 8*(r>>2) + 4*(lane>>5)
#define ROWF(r) (((r) & 3) + 8 * ((r) >> 2) + 4 * lh)

__device__ __forceinline__ f32x16 mfma16(bf16x8 a, bf16x8 b, f32x16 c) {
    return __builtin_amdgcn_mfma_f32_32x32x16_bf16(a, b, c, 0, 0, 0);
}
__device__ __forceinline__ unsigned short f2bf(float f) {   // RNE
    const unsigned u = __float_as_uint(f);
    return (unsigned short)((u + 0x7FFFu + ((u >> 16) & 1u)) >> 16);
}
__device__ __forceinline__ float bf2f(unsigned short b) {
    return __uint_as_float(((unsigned)b) << 16);
}
// async global->LDS, 16B per lane; lds dest = wave-uniform base + lane*16
__device__ __forceinline__ void gl16(const unsigned short* g, unsigned short* l) {
    __builtin_amdgcn_global_load_lds(
        (const __attribute__((address_space(1))) unsigned int*)g,
        (__attribute__((address_space(3))) unsigned int*)l, 16, 0, 0);
}

// ---- convert R x 256 fp32 -> hi/lo bf16 (row-major) + transposed hi (256 x R) ----
__global__ __launch_bounds__(256) void k_convert(const float* __restrict__ src,
        unsigned short* __restrict__ hi, unsigned short* __restrict__ lo,
        unsigned short* __restrict__ hiT, int R) {
    __shared__ unsigned short lh_s[64][65];
    const int r0 = blockIdx.x * 64, k0 = blockIdx.y * 64, t = threadIdx.x;
#pragma unroll
    for (int it = 0; it < 4; ++it) {
        const int idx = t + 256 * it;
        const int rl = idx >> 4, kq = idx & 15;
        const float4 v = *(const float4*)(src + (size_t)(r0 + rl) * DDIM + k0 + kq * 4);
        const unsigned short h0 = f2bf(v.x), h1 = f2bf(v.y), h2 = f2bf(v.z), h3 = f2bf(v.w);
        const unsigned short l0 = f2bf(v.x - bf2f(h0)), l1 = f2bf(v.y - bf2f(h1));
        const unsigned short l2 = f2bf(v.z - bf2f(h2)), l3 = f2bf(v.w - bf2f(h3));
        ushort4 hv; hv.x = h0; hv.y = h1; hv.z = h2; hv.w = h3;
        ushort4 lv; lv.x = l0; lv.y = l1; lv.z = l2; lv.w = l3;
        *(ushort4*)(hi + (size_t)(r0 + rl) * DDIM + k0 + kq * 4) = hv;
        *(ushort4*)(lo + (size_t)(r0 + rl) * DDIM + k0 + kq * 4) = lv;
        lh_s[rl][kq * 4 + 0] = h0; lh_s[rl][kq * 4 + 1] = h1;
        lh_s[rl][kq * 4 + 2] = h2; lh_s[rl][kq * 4 + 3] = h3;
    }
    __syncthreads();
#pragma unroll
    for (int it = 0; it < 16; ++it) {
        const int idx = t + 256 * it;           // 0..4095
        const int kl = idx >> 6, rl = idx & 63;
        hiT[(size_t)(k0 + kl) * R + r0 + rl] = lh_s[rl][kl];
    }
}

// ---- per-row 6*||row|| for Q and M ----
__global__ __launch_bounds__(256) void k_norms(const float* __restrict__ Q,
        const float* __restrict__ M, float* __restrict__ qn6, float* __restrict__ mn6) {
    const int wave = blockIdx.x * 4 + (threadIdx.x >> 6);
    const int lane = threadIdx.x & 63;
    const float* src; float* dst;
    if (wave < NQ) { src = Q + (size_t)wave * DDIM; dst = qn6 + wave; }
    else { const int r = wave - NQ; if (r >= STOT) return;
           src = M + (size_t)r * DDIM; dst = mn6 + r; }
    const float4 v = *(const float4*)(src + lane * 4);
    float ss = v.x * v.x + v.y * v.y + v.z * v.z + v.w * v.w;
#pragma unroll
    for (int sh = 1; sh < 64; sh <<= 1) ss += __shfl_xor(ss, sh, 64);
    if (lane == 0) *dst = 6.0f * sqrtf(ss);
}

// ---- main GEMM pass (LDS-staged): logits -> P' (row-shift) + E' (col-shift, masked, transposed) ----
// grid (12 j, ch/128 i); block 256 = 4 waves (2i x 2j), wave tile 64x64, BK=32 staged.
__global__ __launch_bounds__(256) void k_pe(
        const unsigned short* __restrict__ Qhi, const unsigned short* __restrict__ Qlo,
        const unsigned short* __restrict__ Mhi, const unsigned short* __restrict__ Mlo,
        const int* __restrict__ labels, const float* __restrict__ qn6,
        const float* __restrict__ mn6,
        unsigned short* __restrict__ P, unsigned short* __restrict__ ET,
        int ibase, int ch) {
    __shared__ unsigned short sA[2][128][BK];   // [hi/lo] Q tile, 16 KB
    __shared__ unsigned short sB[2][128][BK];   // [hi/lo] M tile, 16 KB
    __shared__ unsigned short tr[4][32][40];    // epilogue transpose, 10 KB
    const int t = threadIdx.x, lane = t & 63, wid = t >> 6;
    const int l31 = lane & 31, lh = lane >> 5;
    const int wi = wid >> 1, wj = wid & 1;
    const int iblk = blockIdx.y * 128;          // chunk-local i base of block
    const int jblk = blockIdx.x * 128;          // global slot base of block
    const int iloc0 = iblk + wi * 64;
    const int j0    = jblk + wj * 64;
    const int cblk  = blockIdx.x >> 2;          // class of this j-block

    // staging geometry: chunk = 16B unit; row = chunk>>2, colgroup = chunk&3
    const int ch0 = wid * 64 + lane, ch1 = 256 + wid * 64 + lane;
    const int r0c = ch0 >> 2, x0 = ch0 & 3, r1c = ch1 >> 2, x1 = ch1 & 3;
    const unsigned short* gA[2] = { Qhi + (size_t)(ibase + iblk) * DDIM,
                                    Qlo + (size_t)(ibase + iblk) * DDIM };
    const unsigned short* gB[2] = { Mhi + (size_t)jblk * DDIM,
                                    Mlo + (size_t)jblk * DDIM };

    f32x16 acc[2][2] = {};
    for (int s = 0; s < DDIM / BK; ++s) {
        const int k0 = s * BK;
#pragma unroll
        for (int h = 0; h < 2; ++h) {
            gl16(gA[h] + (size_t)r0c * DDIM + k0 + x0 * 8, &sA[h][0][0] + ch0 * 8);
            gl16(gA[h] + (size_t)r1c * DDIM + k0 + x1 * 8, &sA[h][0][0] + ch1 * 8);
            gl16(gB[h] + (size_t)r0c * DDIM + k0 + x0 * 8, &sB[h][0][0] + ch0 * 8);
            gl16(gB[h] + (size_t)r1c * DDIM + k0 + x1 * 8, &sB[h][0][0] + ch1 * 8);
        }
        __syncthreads();
#pragma unroll
        for (int t16 = 0; t16 < 2; ++t16) {
            const int kc = t16 * 16 + 8 * lh;
            const bf16x8 a0h = *(const bf16x8*)&sA[0][wi * 64 + l31][kc];
            const bf16x8 a1h = *(const bf16x8*)&sA[0][wi * 64 + 32 + l31][kc];
            const bf16x8 a0l = *(const bf16x8*)&sA[1][wi * 64 + l31][kc];
            const bf16x8 a1l = *(const bf16x8*)&sA[1][wi * 64 + 32 + l31][kc];
            const bf16x8 b0h = *(const bf16x8*)&sB[0][wj * 64 + l31][kc];
            const bf16x8 b1h = *(const bf16x8*)&sB[0][wj * 64 + 32 + l31][kc];
            const bf16x8 b0l = *(const bf16x8*)&sB[1][wj * 64 + l31][kc];
            const bf16x8 b1l = *(const bf16x8*)&sB[1][wj * 64 + 32 + l31][kc];
            acc[0][0] = mfma16(a0h, b0h, acc[0][0]);
            acc[0][0] = mfma16(a0h, b0l, acc[0][0]);
            acc[0][0] = mfma16(a0l, b0h, acc[0][0]);
            acc[0][1] = mfma16(a0h, b1h, acc[0][1]);
            acc[0][1] = mfma16(a0h, b1l, acc[0][1]);
            acc[0][1] = mfma16(a0l, b1h, acc[0][1]);
            acc[1][0] = mfma16(a1h, b0h, acc[1][0]);
            acc[1][0] = mfma16(a1h, b0l, acc[1][0]);
            acc[1][0] = mfma16(a1l, b0h, acc[1][0]);
            acc[1][1] = mfma16(a1h, b1h, acc[1][1]);
            acc[1][1] = mfma16(a1h, b1l, acc[1][1]);
            acc[1][1] = mfma16(a1l, b1h, acc[1][1]);
        }
        __syncthreads();
    }

#pragma unroll
    for (int ti = 0; ti < 2; ++ti) {
        float qn[16]; unsigned lm = 0;
        const int ig0 = ibase + iloc0 + ti * 32;
#pragma unroll
        for (int r = 0; r < 16; ++r) {
            const int ir = ig0 + ROWF(r);
            qn[r] = qn6[ir];
            lm |= (unsigned)(labels[ir] == cblk) << r;
        }
#pragma unroll
        for (int tj = 0; tj < 2; ++tj) {
            const int jg = j0 + tj * 32 + l31;
            const float mn = mn6[jg];
#pragma unroll
            for (int r = 0; r < 16; ++r) {
                const float lg = acc[ti][tj][r];
                const int il = iloc0 + ti * 32 + ROWF(r);
                P[(size_t)il * STOT + jg] = f2bf(__expf(lg - qn[r]));
                const float e = ((lm >> r) & 1u) ? __expf(lg - mn) : 0.0f;
                tr[wid][l31][ROWF(r)] = f2bf(e);
            }
            // wave-local LDS transpose -> coalesced ET rows
            const int rr = lane >> 1, off = (lane & 1) * 16;
            const unsigned short* lp = &tr[wid][rr][off];
            const bf16x8 w0 = *(const bf16x8*)(lp);
            const bf16x8 w1 = *(const bf16x8*)(lp + 8);
            unsigned short* erow = ET + (size_t)(j0 + tj * 32 + rr) * ch + iloc0 + ti * 32 + off;
            *(bf16x8*)(erow)     = w0;
            *(bf16x8*)(erow + 8) = w1;
        }
    }
}

// ---- PV + fused rowsum (LDS-staged): out = (P' @ Mhi^T) / rowsum(P') ----
// grid (ch/64, 2); block 256 = 4 waves (2q x 2d), wave = 32q x 64d, BK=32, K=1536.
__global__ __launch_bounds__(256) void k_pv(const unsigned short* __restrict__ P,
        const unsigned short* __restrict__ MhiT,
        float* __restrict__ out, int ibase) {
    __shared__ unsigned short sP[64][BK];    // 4 KB
    __shared__ unsigned short sV[128][BK];   // 8 KB
    const int t = threadIdx.x, lane = t & 63, wid = t >> 6;
    const int l31 = lane & 31, lh = lane >> 5;
    const int wq = wid >> 1, wd = wid & 1;
    const int qblk = blockIdx.x * 64;
    const int dblk = blockIdx.y * 128;
    const int d0 = dblk + wd * 64;

    const int ch0 = wid * 64 + lane, ch1 = 256 + wid * 64 + lane;
    const int r0c = ch0 >> 2, x0 = ch0 & 3, r1c = ch1 >> 2, x1 = ch1 & 3;
    const unsigned short* gP = P + (size_t)qblk * STOT;
    const unsigned short* gV = MhiT + (size_t)dblk * STOT;

    bf16x8 bones;
    const short ob = (l31 == 0) ? (short)0x3F80 : (short)0;
#pragma unroll
    for (int e = 0; e < 8; ++e) bones[e] = ob;

    f32x16 acc[2] = {};
    f32x16 accS = {};
    for (int s = 0; s < STOT / BK; ++s) {
        const int k0 = s * BK;
        // sP: 256 chunks (1 issue), sV: 512 chunks (2 issues)
        gl16(gP + (size_t)(ch0 >> 2) * STOT + k0 + (ch0 & 3) * 8, &sP[0][0] + ch0 * 8);
        gl16(gV + (size_t)r0c * STOT + k0 + x0 * 8, &sV[0][0] + ch0 * 8);
        gl16(gV + (size_t)r1c * STOT + k0 + x1 * 8, &sV[0][0] + ch1 * 8);
        __syncthreads();
#pragma unroll
        for (int t16 = 0; t16 < 2; ++t16) {
            const int kc = t16 * 16 + 8 * lh;
            const bf16x8 a0 = *(const bf16x8*)&sP[wq * 32 + l31][kc];
            const bf16x8 b0 = *(const bf16x8*)&sV[wd * 64 + l31][kc];
            const bf16x8 b1 = *(const bf16x8*)&sV[wd * 64 + 32 + l31][kc];
            acc[0] = mfma16(a0, b0, acc[0]);
            acc[1] = mfma16(a0, b1, acc[1]);
            accS   = mfma16(a0, bones, accS);
        }
        __syncthreads();
    }
    float rinv[16];
#pragma unroll
    for (int r = 0; r < 16; ++r) rinv[r] = 1.f / __shfl(accS[r], lh << 5, 64);
#pragma unroll
    for (int td = 0; td < 2; ++td) {
#pragma unroll
        for (int r = 0; r < 16; ++r) {
            const int ig = ibase + qblk + wq * 32 + ROWF(r);
            out[(size_t)ig * DDIM + d0 + td * 32 + l31] = acc[td][r] * rinv[r];
        }
    }
}

// ---- delta + fused colsum (LDS-staged): delta[j][d] += sum_i ET[j][i]*QhiT[d][i] ----
// grid (12 j, 2 d, ch/512 ksplit); block 256 = 4 waves (2j x 2d), BK=32, K=512/block.
__global__ __launch_bounds__(256) void k_delta4(const unsigned short* __restrict__ ET,
        const unsigned short* __restrict__ QhiT,
        float* __restrict__ delta, float* __restrict__ colsum, int ibase, int ch) {
    __shared__ unsigned short sE[128][BK];   // 8 KB
    __shared__ unsigned short sQ[128][BK];   // 8 KB
    const int t = threadIdx.x, lane = t & 63, wid = t >> 6;
    const int l31 = lane & 31, lh = lane >> 5;
    const int wj = wid >> 1, wd = wid & 1;
    const int jblk = blockIdx.x * 128, dblk = blockIdx.y * 128;
    const int j0 = jblk + wj * 64, d0 = dblk + wd * 64;
    const int i0 = blockIdx.z * 512;

    const int ch0 = wid * 64 + lane, ch1 = 256 + wid * 64 + lane;
    const int r0c = ch0 >> 2, x0 = ch0 & 3, r1c = ch1 >> 2, x1 = ch1 & 3;
    const unsigned short* gE = ET + (size_t)jblk * ch + i0;
    const unsigned short* gQ = QhiT + (size_t)dblk * NQ + ibase + i0;

    bf16x8 bones;
    const short ob = (l31 == 0) ? (short)0x3F80 : (short)0;
#pragma unroll
    for (int e = 0; e < 8; ++e) bones[e] = ob;

    f32x16 acc[2][2] = {};
    f32x16 accS0 = {}, accS1 = {};
    for (int s = 0; s < 512 / BK; ++s) {
        const int k0 = s * BK;
        gl16(gE + (size_t)r0c * ch + k0 + x0 * 8, &sE[0][0] + ch0 * 8);
        gl16(gE + (size_t)r1c * ch + k0 + x1 * 8, &sE[0][0] + ch1 * 8);
        gl16(gQ + (size_t)r0c * NQ + k0 + x0 * 8, &sQ[0][0] + ch0 * 8);
        gl16(gQ + (size_t)r1c * NQ + k0 + x1 * 8, &sQ[0][0] + ch1 * 8);
        __syncthreads();
#pragma unroll
        for (int t16 = 0; t16 < 2; ++t16) {
            const int kc = t16 * 16 + 8 * lh;
            const bf16x8 a0 = *(const bf16x8*)&sE[wj * 64 + l31][kc];
            const bf16x8 a1 = *(const bf16x8*)&sE[wj * 64 + 32 + l31][kc];
            const bf16x8 b0 = *(const bf16x8*)&sQ[wd * 64 + l31][kc];
            const bf16x8 b1 = *(const bf16x8*)&sQ[wd * 64 + 32 + l31][kc];
            acc[0][0] = mfma16(a0, b0, acc[0][0]);
            acc[0][1] = mfma16(a0, b1, acc[0][1]);
            acc[1][0] = mfma16(a1, b0, acc[1][0]);
            acc[1][1] = mfma16(a1, b1, acc[1][1]);
            if (wd == 0) {                       // wave-uniform branch
                accS0 = mfma16(a0, bones, accS0);
                accS1 = mfma16(a1, bones, accS1);
            }
        }
        __syncthreads();
    }
#pragma unroll
    for (int tj = 0; tj < 2; ++tj) {
#pragma unroll
        for (int td = 0; td < 2; ++td) {
#pragma unroll
            for (int r = 0; r < 16; ++r) {
                const int jr = j0 + tj * 32 + ROWF(r);
                atomicAdd(&delta[(size_t)jr * DDIM + d0 + td * 32 + l31], acc[tj][td][r]);
            }
        }
    }
    if (wd == 0 && l31 == 0) {   // lanes 0 and 32 (lh=0/1) cover all 32 rows
#pragma unroll
        for (int r = 0; r < 16; ++r) {
            atomicAdd(&colsum[j0 + ROWF(r)], accS0[r]);
            atomicAdd(&colsum[j0 + 32 + ROWF(r)], accS1[r]);
        }
    }
}

// ---- finalize memory: new = M + delta/colsum, row-normalize ----
__global__ void k_final(const float* __restrict__ M,
                        const float* __restrict__ delta,
                        const float* __restrict__ colsum,
                        float* __restrict__ out) {
    const int row  = blockIdx.x * 4 + (threadIdx.x >> 6);
    const int lane = threadIdx.x & 63;
    const float inv = 1.f / colsum[row];
    const float4 mv = *(const float4*)(M + (size_t)row * DDIM + lane * 4);
    const float4 dv = *(const float4*)(delta + (size_t)row * DDIM + lane * 4);
    float4 nv;
    nv.x = fmaf(dv.x, inv, mv.x);
    nv.y = fmaf(dv.y, inv, mv.y);
    nv.z = fmaf(dv.z, inv, mv.z);
    nv.w = fmaf(dv.w, inv, mv.w);
    float ss = nv.x * nv.x + nv.y * nv.y + nv.z * nv.z + nv.w * nv.w;
#pragma unroll
    for (int sh = 1; sh < 64; sh <<= 1) ss += __shfl_xor(ss, sh, 64);
    const float rn = 1.f / fmaxf(sqrtf(ss), 1e-12f);
    nv.x *= rn; nv.y *= rn; nv.z *= rn; nv.w *= rn;
    *(float4*)(out + (size_t)NQ * DDIM + (size_t)row * DDIM + lane * 4) = nv;
}

extern "C" void kernel_launch(void* const* d_in, const int* in_sizes, int n_in,
                              void* d_out, int out_size, void* d_ws, size_t ws_size,
                              hipStream_t stream) {
    const float* Q      = (const float*)d_in[0];
    const int*   labels = (const int*)d_in[1];
    const float* M      = (const float*)d_in[2];
    float* out = (float*)d_out;

    // ---- workspace layout (colsum+delta first: they get memset) ----
    char* p = (char*)d_ws;
    float* colsum = (float*)p;          p += (size_t)STOT * 4;
    float* delta  = (float*)p;          p += (size_t)STOT * DDIM * 4;
    float* qn6    = (float*)p;          p += (size_t)NQ * 4;
    float* mn6    = (float*)p;          p += (size_t)STOT * 4;
    unsigned short* Qhi  = (unsigned short*)p; p += (size_t)NQ * DDIM * 2;
    unsigned short* Qlo  = (unsigned short*)p; p += (size_t)NQ * DDIM * 2;
    unsigned short* QhiT = (unsigned short*)p; p += (size_t)NQ * DDIM * 2;
    unsigned short* Mhi  = (unsigned short*)p; p += (size_t)STOT * DDIM * 2;
    unsigned short* Mlo  = (unsigned short*)p; p += (size_t)STOT * DDIM * 2;
    unsigned short* MhiT = (unsigned short*)p; p += (size_t)STOT * DDIM * 2;
    const size_t fixed_bytes = (size_t)(p - (char*)d_ws);

    // adaptive chunking: P' (ch x 1536) + ET (1536 x ch), both bf16
    int nch = 2;
    while (nch < 64 &&
           fixed_bytes + (size_t)(NQ / nch) * STOT * 2 * 2 > ws_size) nch <<= 1;
    const int ch = NQ / nch;
    unsigned short* Pbuf = (unsigned short*)p;
    unsigned short* ETb  = Pbuf + (size_t)ch * STOT;

    hipMemsetAsync(d_ws, 0, (size_t)(STOT + STOT * DDIM) * 4, stream);  // colsum+delta

    k_convert<<<dim3(NQ / 64, 4), 256, 0, stream>>>(Q, Qhi, Qlo, QhiT, NQ);
    k_convert<<<dim3(STOT / 64, 4), 256, 0, stream>>>(M, Mhi, Mlo, MhiT, STOT);
    k_norms<<<(NQ + STOT) / 4, 256, 0, stream>>>(Q, M, qn6, mn6);

    for (int h = 0; h < nch; ++h) {
        const int ibase = h * ch;
        k_pe<<<dim3(12, ch / 128), 256, 0, stream>>>(Qhi, Qlo, Mhi, Mlo, labels,
                                                     qn6, mn6, Pbuf, ETb, ibase, ch);
        k_pv<<<dim3(ch / 64, 2), 256, 0, stream>>>(Pbuf, MhiT, out, ibase);
        k_delta4<<<dim3(STOT / 128, 2, ch / 512), 256, 0, stream>>>(ETb, QhiT, delta,
                                                                    colsum, ibase, ch);
    }
    k_final<<<STOT / 4, 256, 0, stream>>>(M, delta, colsum, out);
}

// Round 5
// 303.938 us; speedup vs baseline: 18.7029x; 1.2329x over previous
//
#include <hip/hip_runtime.h>
#include <math.h>

#define NQ    32768
#define DDIM  256
#define NCLS  3
#define CELLS 512
#define STOT  1536   // NCLS*CELLS
#define BK    32     // k_pe K-step

typedef __attribute__((ext_vector_type(8)))  short bf16x8;
typedef __attribute__((ext_vector_type(16))) float f32x16;

// C-fragment row map for 32x32 MFMA: row = (r&3) + 8*(r>>2) + 4*(lane>>5)
#define ROWF(r) (((r) & 3) + 8 * ((r) >> 2) + 4 * lh)

__device__ __forceinline__ f32x16 mfma16(bf16x8 a, bf16x8 b, f32x16 c) {
    return __builtin_amdgcn_mfma_f32_32x32x16_bf16(a, b, c, 0, 0, 0);
}
__device__ __forceinline__ unsigned short f2bf(float f) {   // RNE
    const unsigned u = __float_as_uint(f);
    return (unsigned short)((u + 0x7FFFu + ((u >> 16) & 1u)) >> 16);
}
__device__ __forceinline__ float bf2f(unsigned short b) {
    return __uint_as_float(((unsigned)b) << 16);
}
// async global->LDS, 16B per lane; lds dest = wave-uniform base + lane*16
__device__ __forceinline__ void gl16(const unsigned short* g, unsigned short* l) {
    __builtin_amdgcn_global_load_lds(
        (const __attribute__((address_space(1))) unsigned int*)g,
        (__attribute__((address_space(3))) unsigned int*)l, 16, 0, 0);
}

// ---- convert R x 256 fp32 -> hi/lo bf16 (row-major) + transposed hi + row sumsq ----
__global__ __launch_bounds__(256) void k_convert(const float* __restrict__ src,
        unsigned short* __restrict__ hi, unsigned short* __restrict__ lo,
        unsigned short* __restrict__ hiT, float* __restrict__ sq, int R) {
    __shared__ unsigned short lh_s[64][65];
    const int r0 = blockIdx.x * 64, k0 = blockIdx.y * 64, t = threadIdx.x;
#pragma unroll
    for (int it = 0; it < 4; ++it) {
        const int idx = t + 256 * it;
        const int rl = idx >> 4, kq = idx & 15;
        const float4 v = *(const float4*)(src + (size_t)(r0 + rl) * DDIM + k0 + kq * 4);
        const unsigned short h0 = f2bf(v.x), h1 = f2bf(v.y), h2 = f2bf(v.z), h3 = f2bf(v.w);
        const unsigned short l0 = f2bf(v.x - bf2f(h0)), l1 = f2bf(v.y - bf2f(h1));
        const unsigned short l2 = f2bf(v.z - bf2f(h2)), l3 = f2bf(v.w - bf2f(h3));
        ushort4 hv; hv.x = h0; hv.y = h1; hv.z = h2; hv.w = h3;
        ushort4 lv; lv.x = l0; lv.y = l1; lv.z = l2; lv.w = l3;
        *(ushort4*)(hi + (size_t)(r0 + rl) * DDIM + k0 + kq * 4) = hv;
        *(ushort4*)(lo + (size_t)(r0 + rl) * DDIM + k0 + kq * 4) = lv;
        lh_s[rl][kq * 4 + 0] = h0; lh_s[rl][kq * 4 + 1] = h1;
        lh_s[rl][kq * 4 + 2] = h2; lh_s[rl][kq * 4 + 3] = h3;
        float ssq = v.x * v.x + v.y * v.y + v.z * v.z + v.w * v.w;
        ssq += __shfl_xor(ssq, 1, 64);
        ssq += __shfl_xor(ssq, 2, 64);
        ssq += __shfl_xor(ssq, 4, 64);
        ssq += __shfl_xor(ssq, 8, 64);
        if (kq == 0) atomicAdd(&sq[r0 + rl], ssq);
    }
    __syncthreads();
#pragma unroll
    for (int it = 0; it < 16; ++it) {
        const int idx = t + 256 * it;           // 0..4095
        const int kl = idx >> 6, rl = idx & 63;
        hiT[(size_t)(k0 + kl) * R + r0 + rl] = lh_s[rl][kl];
    }
}

// ---- main GEMM pass (dbuf LDS, swizzled): logits -> P' + E'^T ----
// 1D grid 12*(ch/128) with XCD co-location of the 12 j-blocks per i-panel.
__global__ __launch_bounds__(256) void k_pe(
        const unsigned short* __restrict__ Qhi, const unsigned short* __restrict__ Qlo,
        const unsigned short* __restrict__ Mhi, const unsigned short* __restrict__ Mlo,
        const int* __restrict__ labels, const float* __restrict__ qn2,
        const float* __restrict__ mn2,
        unsigned short* __restrict__ P, unsigned short* __restrict__ ET,
        int ibase, int ch, int ipg) {
    __shared__ unsigned short smem[2][2][2][128][BK];  // [buf][A/B][hi/lo] = 64 KB
    typedef unsigned short trt[32][40];
    trt* tr = (trt*)&smem[0][0][0][0][0];              // epilogue overlay on buf0

    const int t = threadIdx.x, lane = t & 63, wid = t >> 6;
    const int l31 = lane & 31, lh = lane >> 5;
    const int wi = wid >> 1, wj = wid & 1;
    int ib, jb;
    if (ipg > 0) {
        const int xcd = blockIdx.x & 7, s = blockIdx.x >> 3;
        jb = s % 12; ib = xcd * ipg + s / 12;
    } else { jb = blockIdx.x % 12; ib = blockIdx.x / 12; }
    const int iblk = ib * 128, jblk = jb * 128;
    const int iloc0 = iblk + wi * 64;
    const int j0    = jblk + wj * 64;
    const int cblk  = jb >> 2;

    // staging: 512 chunks/tile, 2 per thread; src chunk XOR-swizzled within row
    const int c0 = wid * 128 + lane, c1 = c0 + 64;
    const int r0 = c0 >> 2, o0 = ((c0 & 3) ^ (r0 & 3)) * 8;
    const int r1 = c1 >> 2, o1 = ((c1 & 3) ^ (r1 & 3)) * 8;
    const unsigned short* gA[2] = { Qhi + (size_t)(ibase + iblk) * DDIM,
                                    Qlo + (size_t)(ibase + iblk) * DDIM };
    const unsigned short* gB[2] = { Mhi + (size_t)jblk * DDIM,
                                    Mlo + (size_t)jblk * DDIM };
    auto STAGE = [&](int b, int k0) {
#pragma unroll
        for (int h = 0; h < 2; ++h) {
            gl16(gA[h] + (size_t)r0 * DDIM + k0 + o0, &smem[b][0][h][0][0] + c0 * 8);
            gl16(gA[h] + (size_t)r1 * DDIM + k0 + o1, &smem[b][0][h][0][0] + c1 * 8);
            gl16(gB[h] + (size_t)r0 * DDIM + k0 + o0, &smem[b][1][h][0][0] + c0 * 8);
            gl16(gB[h] + (size_t)r1 * DDIM + k0 + o1, &smem[b][1][h][0][0] + c1 * 8);
        }
    };

    f32x16 acc[2][2] = {};
    const int ra0 = wi * 64 + l31, ra1 = ra0 + 32;
    const int rb0 = wj * 64 + l31, rb1 = rb0 + 32;
    STAGE(0, 0);
    for (int s = 0; s < DDIM / BK; ++s) {
        __syncthreads();                    // buf s&1 staged; prev reads done
        if (s + 1 < DDIM / BK) STAGE((s + 1) & 1, (s + 1) * BK);
        const int b = s & 1;
#pragma unroll
        for (int t16 = 0; t16 < 2; ++t16) {
            const int oc = t16 * 2 + lh;
            const bf16x8 a0h = *(const bf16x8*)&smem[b][0][0][ra0][(oc ^ (ra0 & 3)) * 8];
            const bf16x8 a1h = *(const bf16x8*)&smem[b][0][0][ra1][(oc ^ (ra1 & 3)) * 8];
            const bf16x8 a0l = *(const bf16x8*)&smem[b][0][1][ra0][(oc ^ (ra0 & 3)) * 8];
            const bf16x8 a1l = *(const bf16x8*)&smem[b][0][1][ra1][(oc ^ (ra1 & 3)) * 8];
            const bf16x8 b0h = *(const bf16x8*)&smem[b][1][0][rb0][(oc ^ (rb0 & 3)) * 8];
            const bf16x8 b1h = *(const bf16x8*)&smem[b][1][0][rb1][(oc ^ (rb1 & 3)) * 8];
            const bf16x8 b0l = *(const bf16x8*)&smem[b][1][1][rb0][(oc ^ (rb0 & 3)) * 8];
            const bf16x8 b1l = *(const bf16x8*)&smem[b][1][1][rb1][(oc ^ (rb1 & 3)) * 8];
            acc[0][0] = mfma16(a0h, b0h, acc[0][0]);
            acc[0][0] = mfma16(a0h, b0l, acc[0][0]);
            acc[0][0] = mfma16(a0l, b0h, acc[0][0]);
            acc[0][1] = mfma16(a0h, b1h, acc[0][1]);
            acc[0][1] = mfma16(a0h, b1l, acc[0][1]);
            acc[0][1] = mfma16(a0l, b1h, acc[0][1]);
            acc[1][0] = mfma16(a1h, b0h, acc[1][0]);
            acc[1][0] = mfma16(a1h, b0l, acc[1][0]);
            acc[1][0] = mfma16(a1l, b0h, acc[1][0]);
            acc[1][1] = mfma16(a1h, b1h, acc[1][1]);
            acc[1][1] = mfma16(a1h, b1l, acc[1][1]);
            acc[1][1] = mfma16(a1l, b1h, acc[1][1]);
        }
    }
    __syncthreads();   // all waves done with smem before tr overlay

#pragma unroll
    for (int ti = 0; ti < 2; ++ti) {
        float qn[16]; unsigned lm = 0;
        const int ig0 = ibase + iloc0 + ti * 32;
#pragma unroll
        for (int r = 0; r < 16; ++r) {
            const int ir = ig0 + ROWF(r);
            qn[r] = 6.0f * sqrtf(qn2[ir]);
            lm |= (unsigned)(labels[ir] == cblk) << r;
        }
#pragma unroll
        for (int tj = 0; tj < 2; ++tj) {
            const int jg = j0 + tj * 32 + l31;
            const float mn = 6.0f * sqrtf(mn2[jg]);
#pragma unroll
            for (int r = 0; r < 16; ++r) {
                const float lg = acc[ti][tj][r];
                const int il = iloc0 + ti * 32 + ROWF(r);
                P[(size_t)il * STOT + jg] = f2bf(__expf(lg - qn[r]));
                const float e = ((lm >> r) & 1u) ? __expf(lg - mn) : 0.0f;
                tr[wid][l31][ROWF(r)] = f2bf(e);
            }
            const int rr = lane >> 1, off = (lane & 1) * 16;
            const unsigned short* lp = &tr[wid][rr][off];
            const bf16x8 w0 = *(const bf16x8*)(lp);
            const bf16x8 w1 = *(const bf16x8*)(lp + 8);
            unsigned short* erow = ET + (size_t)(j0 + tj * 32 + rr) * ch + iloc0 + ti * 32 + off;
            *(bf16x8*)(erow)     = w0;
            *(bf16x8*)(erow + 8) = w1;
        }
    }
}

// ---- PV + fused rowsum (dbuf, BK=64, swizzled): out = (P' @ Mhi^T) / rowsum ----
// grid (ch/64, 2); block 4 waves (2q x 2d), wave 32q x 64d.
__global__ __launch_bounds__(256) void k_pv(const unsigned short* __restrict__ P,
        const unsigned short* __restrict__ MhiT,
        float* __restrict__ out, int ibase) {
    __shared__ unsigned short sP[2][64][64];    // 16 KB
    __shared__ unsigned short sV[2][128][64];   // 32 KB
    const int t = threadIdx.x, lane = t & 63, wid = t >> 6;
    const int l31 = lane & 31, lh = lane >> 5;
    const int wq = wid >> 1, wd = wid & 1;
    const int qblk = blockIdx.x * 64, dblk = blockIdx.y * 128;
    const int d0 = dblk + wd * 64;
    const unsigned short* gP = P + (size_t)qblk * STOT;
    const unsigned short* gV = MhiT + (size_t)dblk * STOT;

    auto STAGE = [&](int b, int k0) {
#pragma unroll
        for (int it = 0; it < 2; ++it) {
            const int c = wid * 128 + it * 64 + lane;
            const int r = c >> 3, o = ((c & 7) ^ (r & 7)) * 8;
            gl16(gP + (size_t)r * STOT + k0 + o, &sP[b][0][0] + c * 8);
        }
#pragma unroll
        for (int it = 0; it < 4; ++it) {
            const int c = wid * 256 + it * 64 + lane;
            const int r = c >> 3, o = ((c & 7) ^ (r & 7)) * 8;
            gl16(gV + (size_t)r * STOT + k0 + o, &sV[b][0][0] + c * 8);
        }
    };

    bf16x8 bones;
    const short ob = (l31 == 0) ? (short)0x3F80 : (short)0;
#pragma unroll
    for (int e = 0; e < 8; ++e) bones[e] = ob;

    f32x16 acc[2] = {};
    f32x16 accS = {};
    const int rp = wq * 32 + l31, rv0 = wd * 64 + l31, rv1 = rv0 + 32;
    STAGE(0, 0);
    for (int s = 0; s < STOT / 64; ++s) {
        __syncthreads();
        if (s + 1 < STOT / 64) STAGE((s + 1) & 1, (s + 1) * 64);
        const int b = s & 1;
#pragma unroll
        for (int t16 = 0; t16 < 4; ++t16) {
            const int oc = t16 * 2 + lh;
            const bf16x8 a0 = *(const bf16x8*)&sP[b][rp][(oc ^ (rp & 7)) * 8];
            const bf16x8 b0 = *(const bf16x8*)&sV[b][rv0][(oc ^ (rv0 & 7)) * 8];
            const bf16x8 b1 = *(const bf16x8*)&sV[b][rv1][(oc ^ (rv1 & 7)) * 8];
            acc[0] = mfma16(a0, b0, acc[0]);
            acc[1] = mfma16(a0, b1, acc[1]);
            accS   = mfma16(a0, bones, accS);
        }
    }
    float rinv[16];
#pragma unroll
    for (int r = 0; r < 16; ++r) rinv[r] = 1.f / __shfl(accS[r], lh << 5, 64);
#pragma unroll
    for (int td = 0; td < 2; ++td) {
#pragma unroll
        for (int r = 0; r < 16; ++r) {
            const int ig = ibase + qblk + wq * 32 + ROWF(r);
            out[(size_t)ig * DDIM + d0 + td * 32 + l31] = acc[td][r] * rinv[r];
        }
    }
}

// ---- delta + fused colsum (dbuf, BK=64, swizzled, K=1024/block, XCD remap) ----
__global__ __launch_bounds__(256) void k_delta4(const unsigned short* __restrict__ ET,
        const unsigned short* __restrict__ QhiT,
        float* __restrict__ delta, float* __restrict__ colsum,
        int ibase, int ch, int ppx) {
    __shared__ unsigned short sE[2][128][64];   // 32 KB
    __shared__ unsigned short sQ[2][128][64];   // 32 KB
    const int t = threadIdx.x, lane = t & 63, wid = t >> 6;
    const int l31 = lane & 31, lh = lane >> 5;
    const int wj = wid >> 1, wd = wid & 1;
    int jb, db, kb;
    if (ppx > 0) {
        const int xcd = blockIdx.x & 7, s = blockIdx.x >> 3;
        jb = s % 12;
        const int pidx = xcd * ppx + s / 12;
        kb = pidx >> 1; db = pidx & 1;
    } else {
        jb = blockIdx.x % 12; db = (blockIdx.x / 12) & 1; kb = blockIdx.x / 24;
    }
    const int jblk = jb * 128, dblk = db * 128, i0 = kb * 1024;
    const int j0 = jblk + wj * 64, d0 = dblk + wd * 64;
    const unsigned short* gE = ET + (size_t)jblk * ch + i0;
    const unsigned short* gQ = QhiT + (size_t)dblk * NQ + ibase + i0;

    auto STAGE = [&](int b, int k0) {
#pragma unroll
        for (int it = 0; it < 4; ++it) {
            const int c = wid * 256 + it * 64 + lane;
            const int r = c >> 3, o = ((c & 7) ^ (r & 7)) * 8;
            gl16(gE + (size_t)r * ch + k0 + o, &sE[b][0][0] + c * 8);
            gl16(gQ + (size_t)r * NQ + k0 + o, &sQ[b][0][0] + c * 8);
        }
    };

    bf16x8 bones;
    const short ob = (l31 == 0) ? (short)0x3F80 : (short)0;
#pragma unroll
    for (int e = 0; e < 8; ++e) bones[e] = ob;

    f32x16 acc[2][2] = {};
    f32x16 accS0 = {}, accS1 = {};
    const int re0 = wj * 64 + l31, re1 = re0 + 32;
    const int rq0 = wd * 64 + l31, rq1 = rq0 + 32;
    STAGE(0, 0);
    for (int s = 0; s < 16; ++s) {
        __syncthreads();
        if (s + 1 < 16) STAGE((s + 1) & 1, (s + 1) * 64);
        const int b = s & 1;
#pragma unroll
        for (int t16 = 0; t16 < 4; ++t16) {
            const int oc = t16 * 2 + lh;
            const bf16x8 a0 = *(const bf16x8*)&sE[b][re0][(oc ^ (re0 & 7)) * 8];
            const bf16x8 a1 = *(const bf16x8*)&sE[b][re1][(oc ^ (re1 & 7)) * 8];
            const bf16x8 b0 = *(const bf16x8*)&sQ[b][rq0][(oc ^ (rq0 & 7)) * 8];
            const bf16x8 b1 = *(const bf16x8*)&sQ[b][rq1][(oc ^ (rq1 & 7)) * 8];
            acc[0][0] = mfma16(a0, b0, acc[0][0]);
            acc[0][1] = mfma16(a0, b1, acc[0][1]);
            acc[1][0] = mfma16(a1, b0, acc[1][0]);
            acc[1][1] = mfma16(a1, b1, acc[1][1]);
            if (wd == 0) {                       // wave-uniform branch
                accS0 = mfma16(a0, bones, accS0);
                accS1 = mfma16(a1, bones, accS1);
            }
        }
    }
#pragma unroll
    for (int tj = 0; tj < 2; ++tj) {
#pragma unroll
        for (int td = 0; td < 2; ++td) {
#pragma unroll
            for (int r = 0; r < 16; ++r) {
                const int jr = j0 + tj * 32 + ROWF(r);
                atomicAdd(&delta[(size_t)jr * DDIM + d0 + td * 32 + l31], acc[tj][td][r]);
            }
        }
    }
    if (wd == 0 && l31 == 0) {   // lanes 0 and 32 (lh=0/1) cover all 32 rows
#pragma unroll
        for (int r = 0; r < 16; ++r) {
            atomicAdd(&colsum[j0 + ROWF(r)], accS0[r]);
            atomicAdd(&colsum[j0 + 32 + ROWF(r)], accS1[r]);
        }
    }
}

// ---- finalize memory: new = M + delta/colsum, row-normalize ----
__global__ void k_final(const float* __restrict__ M,
                        const float* __restrict__ delta,
                        const float* __restrict__ colsum,
                        float* __restrict__ out) {
    const int row  = blockIdx.x * 4 + (threadIdx.x >> 6);
    const int lane = threadIdx.x & 63;
    const float inv = 1.f / colsum[row];
    const float4 mv = *(const float4*)(M + (size_t)row * DDIM + lane * 4);
    const float4 dv = *(const float4*)(delta + (size_t)row * DDIM + lane * 4);
    float4 nv;
    nv.x = fmaf(dv.x, inv, mv.x);
    nv.y = fmaf(dv.y, inv, mv.y);
    nv.z = fmaf(dv.z, inv, mv.z);
    nv.w = fmaf(dv.w, inv, mv.w);
    float ss = nv.x * nv.x + nv.y * nv.y + nv.z * nv.z + nv.w * nv.w;
#pragma unroll
    for (int sh = 1; sh < 64; sh <<= 1) ss += __shfl_xor(ss, sh, 64);
    const float rn = 1.f / fmaxf(sqrtf(ss), 1e-12f);
    nv.x *= rn; nv.y *= rn; nv.z *= rn; nv.w *= rn;
    *(float4*)(out + (size_t)NQ * DDIM + (size_t)row * DDIM + lane * 4) = nv;
}

extern "C" void kernel_launch(void* const* d_in, const int* in_sizes, int n_in,
                              void* d_out, int out_size, void* d_ws, size_t ws_size,
                              hipStream_t stream) {
    const float* Q      = (const float*)d_in[0];
    const int*   labels = (const int*)d_in[1];
    const float* M      = (const float*)d_in[2];
    float* out = (float*)d_out;

    // ---- workspace layout (memset region first) ----
    char* p = (char*)d_ws;
    float* colsum = (float*)p;          p += (size_t)STOT * 4;
    float* delta  = (float*)p;          p += (size_t)STOT * DDIM * 4;
    float* qn2    = (float*)p;          p += (size_t)NQ * 4;
    float* mn2    = (float*)p;          p += (size_t)STOT * 4;
    const size_t zero_bytes = (size_t)(p - (char*)d_ws);
    unsigned short* Qhi  = (unsigned short*)p; p += (size_t)NQ * DDIM * 2;
    unsigned short* Qlo  = (unsigned short*)p; p += (size_t)NQ * DDIM * 2;
    unsigned short* QhiT = (unsigned short*)p; p += (size_t)NQ * DDIM * 2;
    unsigned short* Mhi  = (unsigned short*)p; p += (size_t)STOT * DDIM * 2;
    unsigned short* Mlo  = (unsigned short*)p; p += (size_t)STOT * DDIM * 2;
    unsigned short* MhiT = (unsigned short*)p; p += (size_t)STOT * DDIM * 2;
    const size_t fixed_bytes = (size_t)(p - (char*)d_ws);

    // adaptive chunking: P' (ch x 1536) + ET (1536 x ch), both bf16; ch % 1024 == 0
    int nch = 2;
    while (nch < 32 &&
           fixed_bytes + (size_t)(NQ / nch) * STOT * 2 * 2 > ws_size) nch <<= 1;
    const int ch = NQ / nch;
    unsigned short* Pbuf = (unsigned short*)p;
    unsigned short* ETb  = Pbuf + (size_t)ch * STOT;

    const int ipg    = ((ch / 128) % 8 == 0) ? (ch / 128) / 8 : 0;
    const int ksplit = ch / 1024;
    const int ppx    = ((2 * ksplit) % 8 == 0) ? (2 * ksplit) / 8 : 0;

    hipMemsetAsync(d_ws, 0, zero_bytes, stream);

    k_convert<<<dim3(NQ / 64, 4), 256, 0, stream>>>(Q, Qhi, Qlo, QhiT, qn2, NQ);
    k_convert<<<dim3(STOT / 64, 4), 256, 0, stream>>>(M, Mhi, Mlo, MhiT, mn2, STOT);

    for (int h = 0; h < nch; ++h) {
        const int ibase = h * ch;
        k_pe<<<12 * (ch / 128), 256, 0, stream>>>(Qhi, Qlo, Mhi, Mlo, labels,
                                                  qn2, mn2, Pbuf, ETb, ibase, ch, ipg);
        k_pv<<<dim3(ch / 64, 2), 256, 0, stream>>>(Pbuf, MhiT, out, ibase);
        k_delta4<<<24 * ksplit, 256, 0, stream>>>(ETb, QhiT, delta, colsum,
                                                  ibase, ch, ppx);
    }
    k_final<<<STOT / 4, 256, 0, stream>>>(M, delta, colsum, out);
}